// Round 1
// baseline (559.948 us; speedup 1.0000x reference)
//
#include <hip/hip_runtime.h>

// Problem constants
#define B_ 8
#define L_ 128
#define D_ 768

// ---------------------------------------------------------------------------
// Kernel A: agg[b,i,d] = sum_j adj[b,i,j] * (text[b,j,d] + dep_embed[b,j,i,d])
// One block per (b,i); 192 threads; each thread owns one float4 column (4 d's).
// dep_embed[b,j,i,d]: for fixed (b,i), d contiguous, j stride = L*D floats.
// ---------------------------------------------------------------------------
__global__ __launch_bounds__(192) void agg_kernel(
    const float* __restrict__ text,       // [B][L][D]
    const float* __restrict__ adj,        // [B][L][L]
    const float* __restrict__ dep,        // [B][L][L][D]
    float* __restrict__ agg) {            // [B*L][D]
  const int bi = blockIdx.x;              // b*L + i
  const int b  = bi >> 7;                 // / L_
  const int i  = bi & (L_ - 1);
  const int t  = threadIdx.x;             // 0..191

  __shared__ float adj_s[L_];
  if (t < L_) adj_s[t] = adj[(size_t)bi * L_ + t];
  __syncthreads();

  const float4* text4 = (const float4*)(text + (size_t)b * L_ * D_);
  // base offset b*L*L*D + i*D ; j stride (in float4) = L*D/4
  const float4* dep4  = (const float4*)(dep + ((size_t)(b * L_) * L_ + i) * D_);

  float4 acc = make_float4(0.f, 0.f, 0.f, 0.f);
#pragma unroll 4
  for (int j = 0; j < L_; ++j) {
    const float  a  = adj_s[j];
    const float4 tx = text4[j * (D_ / 4) + t];
    const float4 dv = dep4[(size_t)j * (L_ * D_ / 4) + t];
    acc.x += a * (tx.x + dv.x);
    acc.y += a * (tx.y + dv.y);
    acc.z += a * (tx.z + dv.z);
    acc.w += a * (tx.w + dv.w);
  }
  ((float4*)(agg + (size_t)bi * D_))[t] = acc;
}

// ---------------------------------------------------------------------------
// Kernel B: out[m][n] = relu( sum_k agg[m][k] * W[k][n] + bias[n] )
// M=1024, N=768, K=768. 64x64 tile per block, 256 threads, 4x4 per thread.
// ---------------------------------------------------------------------------
#define TM 64
#define TN 64
#define TK 32

__global__ __launch_bounds__(256) void gemm_bias_relu(
    const float* __restrict__ A,          // [M][K]  (agg)
    const float* __restrict__ W,          // [K][N]
    const float* __restrict__ bias,       // [N]
    float* __restrict__ out) {            // [M][N]
  __shared__ float As[TM][TK + 4];        // +4 pad: keeps 16B alignment, breaks conflicts
  __shared__ float Bs[TK][TN];

  const int tid = threadIdx.x;
  const int tx  = tid & 15;               // n-direction
  const int ty  = tid >> 4;               // m-direction
  const int m0  = blockIdx.y * TM;
  const int n0  = blockIdx.x * TN;

  // loader indices
  const int ar = tid >> 3;                // 0..31  (A rows; +32 for second half)
  const int ac = (tid & 7) * 4;           // float4 col within K-tile
  const int br = tid >> 4;                // 0..15  (W rows in K-tile; +16 second)
  const int bc = (tid & 15) * 4;          // float4 col within N-tile

  float acc[4][4] = {};

  for (int k0 = 0; k0 < D_; k0 += TK) {
    const float4 a0 = *(const float4*)&A[(size_t)(m0 + ar) * D_ + k0 + ac];
    const float4 a1 = *(const float4*)&A[(size_t)(m0 + ar + 32) * D_ + k0 + ac];
    const float4 b0 = *(const float4*)&W[(size_t)(k0 + br) * D_ + n0 + bc];
    const float4 b1 = *(const float4*)&W[(size_t)(k0 + br + 16) * D_ + n0 + bc];
    __syncthreads();                      // previous tile's reads done before overwrite
    *(float4*)&As[ar][ac]       = a0;
    *(float4*)&As[ar + 32][ac]  = a1;
    *(float4*)&Bs[br][bc]       = b0;
    *(float4*)&Bs[br + 16][bc]  = b1;
    __syncthreads();

#pragma unroll
    for (int kk = 0; kk < TK; ++kk) {
      float av[4];
#pragma unroll
      for (int p = 0; p < 4; ++p) av[p] = As[ty * 4 + p][kk];
      const float4 bv = *(const float4*)&Bs[kk][tx * 4];
      const float bb[4] = {bv.x, bv.y, bv.z, bv.w};
#pragma unroll
      for (int pm = 0; pm < 4; ++pm)
#pragma unroll
        for (int pn = 0; pn < 4; ++pn)
          acc[pm][pn] += av[pm] * bb[pn];
    }
  }

  const float4 bvec = *(const float4*)&bias[n0 + tx * 4];
  const float bias4[4] = {bvec.x, bvec.y, bvec.z, bvec.w};
#pragma unroll
  for (int pm = 0; pm < 4; ++pm) {
    float4 o;
    o.x = fmaxf(acc[pm][0] + bias4[0], 0.f);
    o.y = fmaxf(acc[pm][1] + bias4[1], 0.f);
    o.z = fmaxf(acc[pm][2] + bias4[2], 0.f);
    o.w = fmaxf(acc[pm][3] + bias4[3], 0.f);
    *(float4*)&out[(size_t)(m0 + ty * 4 + pm) * D_ + n0 + tx * 4] = o;
  }
}

extern "C" void kernel_launch(void* const* d_in, const int* in_sizes, int n_in,
                              void* d_out, int out_size, void* d_ws, size_t ws_size,
                              hipStream_t stream) {
  const float* text   = (const float*)d_in[0];  // [B][L][D]
  const float* adj    = (const float*)d_in[1];  // [B][L][L]
  const float* dep    = (const float*)d_in[2];  // [B][L][L][D]
  const float* weight = (const float*)d_in[3];  // [D][D]
  const float* bias   = (const float*)d_in[4];  // [D]
  float* out = (float*)d_out;                   // [B][L][D]
  float* agg = (float*)d_ws;                    // [B*L][D] = 3 MB scratch

  agg_kernel<<<B_ * L_, 192, 0, stream>>>(text, adj, dep, agg);

  dim3 grid(D_ / TN, (B_ * L_) / TM);           // 12 x 16 = 192 blocks
  gemm_bias_relu<<<grid, 256, 0, stream>>>(agg, weight, bias, out);
}

// Round 2
// 545.633 us; speedup vs baseline: 1.0262x; 1.0262x over previous
//
#include <hip/hip_runtime.h>

// Problem constants
#define B_ 8
#define L_ 128
#define D_ 768

typedef float v4f __attribute__((ext_vector_type(4)));

// ---------------------------------------------------------------------------
// Kernel A: agg[b,i,d] = sum_j adj[b,i,j] * (text[b,j,d] + dep_embed[b,j,i,d])
// One block per (b,i); 192 threads; each thread owns one float4 column (4 d's).
// dep_embed is 402 MB streamed exactly once -> nontemporal loads (keep L2 for
// text, which is re-read by 128 blocks per batch). unroll 8 => 16 loads in
// flight per lane for HBM latency hiding.
// ---------------------------------------------------------------------------
__global__ __launch_bounds__(192) void agg_kernel(
    const float* __restrict__ text,       // [B][L][D]
    const float* __restrict__ adj,        // [B][L][L]
    const float* __restrict__ dep,        // [B][L][L][D]
    float* __restrict__ agg) {            // [B*L][D]
  const int bi = blockIdx.x;              // b*L + i
  const int b  = bi >> 7;                 // / L_
  const int i  = bi & (L_ - 1);
  const int t  = threadIdx.x;             // 0..191

  __shared__ float adj_s[L_];
  if (t < L_) adj_s[t] = adj[(size_t)bi * L_ + t];
  __syncthreads();

  const v4f* text4 = (const v4f*)(text + (size_t)b * L_ * D_);
  const v4f* dep4  = (const v4f*)(dep + ((size_t)(b * L_) * L_ + i) * D_);

  v4f acc = {0.f, 0.f, 0.f, 0.f};
#pragma unroll 8
  for (int j = 0; j < L_; ++j) {
    const float a  = adj_s[j];
    const v4f   tx = text4[j * (D_ / 4) + t];
    const v4f   dv = __builtin_nontemporal_load(&dep4[(size_t)j * (L_ * D_ / 4) + t]);
    acc += a * (tx + dv);
  }
  ((v4f*)(agg + (size_t)bi * D_))[t] = acc;
}

// ---------------------------------------------------------------------------
// Kernel B: out[m][n] = relu( sum_k agg[m][k] * W[k][n] + bias[n] )
// M=1024, N=768, K=768. 32x64 tile per block -> 384 blocks (>=1.5 blocks/CU;
// the old 64x64 gave only 192 blocks on 256 CUs = 1 wave/SIMD).
// Register prefetch of the next K-tile is issued immediately after the LDS
// write barrier so global-load latency hides under the inner-product loop.
// A-tile stored transposed [TK][TM+2]: conflict-free writes (2-way max) and
// float2 fragment reads; B-tile reads are 2-way b128 (free).
// ---------------------------------------------------------------------------
#define TM 32
#define TN 64
#define TK 32
#define NKT (D_ / TK)                     // 24 K-tiles

__global__ __launch_bounds__(256) void gemm_bias_relu(
    const float* __restrict__ A,          // [M][K]  (agg)
    const float* __restrict__ W,          // [K][N]
    const float* __restrict__ bias,       // [N]
    float* __restrict__ out) {            // [M][N]
  __shared__ float AsT[TK][TM + 2];       // transposed A tile
  __shared__ float Bs[TK][TN];

  const int tid = threadIdx.x;
  const int tx  = tid & 15;               // n-direction (16 x float4 = 64)
  const int ty  = tid >> 4;               // m-direction (16 x 2 rows = 32)
  const int m0  = blockIdx.y * TM;
  const int n0  = blockIdx.x * TN;

  // loader indices
  const int ar  = tid >> 3;               // 0..31  A row
  const int ac  = (tid & 7) * 4;          // float4 k-col within K-tile
  const int br  = tid >> 4;               // 0..15  W row in K-tile (+16 second)
  const int bc  = (tid & 15) * 4;         // float4 n-col within N-tile

  const float* Arow = A + (size_t)(m0 + ar) * D_ + ac;
  const float* Wrow0 = W + (size_t)br * D_ + n0 + bc;
  const float* Wrow1 = W + (size_t)(br + 16) * D_ + n0 + bc;

  float acc[2][4] = {};

  // prefetch tile 0
  v4f a_reg  = *(const v4f*)Arow;
  v4f b_reg0 = *(const v4f*)Wrow0;
  v4f b_reg1 = *(const v4f*)Wrow1;

  for (int t = 0; t < NKT; ++t) {
    __syncthreads();                      // previous tile's reads done
    AsT[ac + 0][ar] = a_reg.x;
    AsT[ac + 1][ar] = a_reg.y;
    AsT[ac + 2][ar] = a_reg.z;
    AsT[ac + 3][ar] = a_reg.w;
    *(v4f*)&Bs[br][bc]      = b_reg0;
    *(v4f*)&Bs[br + 16][bc] = b_reg1;
    __syncthreads();

    // issue next tile's loads now; they complete under the compute below
    if (t + 1 < NKT) {
      a_reg  = *(const v4f*)(Arow + (t + 1) * TK);
      b_reg0 = *(const v4f*)(Wrow0 + (size_t)(t + 1) * TK * D_);
      b_reg1 = *(const v4f*)(Wrow1 + (size_t)(t + 1) * TK * D_);
    }

#pragma unroll
    for (int kk = 0; kk < TK; ++kk) {
      const float2 av = *(const float2*)&AsT[kk][ty * 2];
      const v4f    bv = *(const v4f*)&Bs[kk][tx * 4];
#pragma unroll
      for (int pn = 0; pn < 4; ++pn) {
        acc[0][pn] += av.x * bv[pn];
        acc[1][pn] += av.y * bv[pn];
      }
    }
  }

  const v4f bvec = *(const v4f*)&bias[n0 + tx * 4];
#pragma unroll
  for (int pm = 0; pm < 2; ++pm) {
    v4f o;
#pragma unroll
    for (int pn = 0; pn < 4; ++pn) o[pn] = fmaxf(acc[pm][pn] + bvec[pn], 0.f);
    *(v4f*)&out[(size_t)(m0 + ty * 2 + pm) * D_ + n0 + tx * 4] = o;
  }
}

extern "C" void kernel_launch(void* const* d_in, const int* in_sizes, int n_in,
                              void* d_out, int out_size, void* d_ws, size_t ws_size,
                              hipStream_t stream) {
  const float* text   = (const float*)d_in[0];  // [B][L][D]
  const float* adj    = (const float*)d_in[1];  // [B][L][L]
  const float* dep    = (const float*)d_in[2];  // [B][L][L][D]
  const float* weight = (const float*)d_in[3];  // [D][D]
  const float* bias   = (const float*)d_in[4];  // [D]
  float* out = (float*)d_out;                   // [B][L][D]
  float* agg = (float*)d_ws;                    // [B*L][D] = 3 MB scratch

  agg_kernel<<<B_ * L_, 192, 0, stream>>>(text, adj, dep, agg);

  dim3 grid(D_ / TN, (B_ * L_) / TM);           // 12 x 32 = 384 blocks
  gemm_bias_relu<<<grid, 256, 0, stream>>>(agg, weight, bias, out);
}